// Round 16
// baseline (1145.253 us; speedup 1.0000x reference)
//
#include <hip/hip_runtime.h>
#include <hip/hip_bf16.h>

typedef unsigned long long ull;

#define BN 4
#define CH 128
#define NP 4096
#define KNB 10
#define EPSI 1e-5f
#define GM_PTS 16
#define CA_PTS 16

#define FMA4(A, W, F) do { (A).x += (W).x*(F); (A).y += (W).y*(F); \
                           (A).z += (W).z*(F); (A).w += (W).w*(F); } while(0)

__device__ __forceinline__ ull shfl_xor_u64(ull v, int mask) {
    unsigned lo = (unsigned)(v & 0xFFFFFFFFu);
    unsigned hi = (unsigned)(v >> 32);
    lo = __shfl_xor(lo, mask);
    hi = __shfl_xor(hi, mask);
    return ((ull)hi << 32) | lo;
}

__device__ __forceinline__ int clampj(int j) { return ((unsigned)j < (unsigned)NP) ? j : 0; }

__device__ __forceinline__ unsigned short f2bf(float f) {   // RNE
    unsigned u = __float_as_uint(f);
    unsigned r = u + 0x7FFFu + ((u >> 16) & 1u);
    return (unsigned short)(r >> 16);
}
__device__ __forceinline__ float bf2f(unsigned short h) {
    return __uint_as_float(((unsigned)h) << 16);
}
__device__ __forceinline__ float4 bfload4(const unsigned short* p) {
    ushort4 h = *(const ushort4*)p;
    float4 r; r.x = bf2f(h.x); r.y = bf2f(h.y); r.z = bf2f(h.z); r.w = bf2f(h.w);
    return r;
}
__device__ __forceinline__ ushort4 bf4(float4 x) {
    ushort4 h; h.x = f2bf(x.x); h.y = f2bf(x.y); h.z = f2bf(x.z); h.w = f2bf(x.w);
    return h;
}

// ---- fused stats commit: per-block atomics + last-block finalize into STATS ----
// Coherence: atomicAdd is device-scope (cross-XCD safe); __syncthreads drains the
// block's atomics (vmcnt(0) before barrier); finalizer re-reads via atomicAdd(+0)
// (RMW -> coherence point, never a stale local cache line). STATS plain writes are
// visible to later kernels via the kernel boundary.
__device__ __forceinline__ void stats_commit(float* __restrict__ SACC,
                                             unsigned* __restrict__ CNT,
                                             float* __restrict__ STATS,
                                             int oslot, int b, int c, int valid,
                                             float ss, float qq, int nblk, float Sdiv) {
    __shared__ int isLast;
    if (valid) {
        atomicAdd(&SACC[((size_t)oslot * (BN * 256) + b * 256 + c) * 2 + 0], ss);
        atomicAdd(&SACC[((size_t)oslot * (BN * 256) + b * 256 + c) * 2 + 1], qq);
    }
    __syncthreads();
    if (threadIdx.x == 0) {
        __threadfence();
        unsigned old = atomicAdd(&CNT[oslot], 1u);
        isLast = (old == (unsigned)(nblk - 1)) ? 1 : 0;
    }
    __syncthreads();
    if (isLast) {
        for (int i = threadIdx.x; i < BN * 256; i += blockDim.x) {
            float sum = atomicAdd(&SACC[((size_t)oslot * (BN * 256) + i) * 2 + 0], 0.f);
            float sq  = atomicAdd(&SACC[((size_t)oslot * (BN * 256) + i) * 2 + 1], 0.f);
            float mean = sum / Sdiv;
            float var = fmaxf(sq / Sdiv - mean * mean, 0.f);
            STATS[((size_t)oslot * (BN * 256) + i) * 2 + 0] = mean;
            STATS[((size_t)oslot * (BN * 256) + i) * 2 + 1] = rsqrtf(var + EPSI);
        }
    }
}

// ---------------- weight packing (all 10 packs in ONE launch) + SACC/CNT zeroing ----
__device__ __forceinline__ void d_packA(const float* w, float* WT, int i) {
    int co = i % CH, ci = (i / CH) % CH, s = i / (CH * CH);
    float val;
    if (s == 0) {
        val = 0.f;
        for (int dk = 0; dk < 3; dk++)
            val += w[(co * 256 + ci) * 3 + dk] - w[(co * 256 + 128 + ci) * 3 + dk];
    } else {
        val = w[(co * 256 + 128 + ci) * 3 + (s - 1)];
    }
    WT[i] = val;
}
__device__ __forceinline__ void d_packB(const float* w, float* WT, int i) {
    int co = i % CH, ci = (i / CH) % CH, dk = i / (CH * CH);
    WT[i] = w[(co * CH + ci) * 3 + dk];
}
__device__ __forceinline__ void d_packUV(const float* w, float* Wu, float* Wn, int Cout, int i) {
    int co = i % Cout, ci = i / Cout;
    float a = w[co * 256 + ci], bb = w[co * 256 + 128 + ci];
    Wu[i] = a - bb; Wn[i] = bb;
}
__device__ __forceinline__ void d_packP(const float* w, float* WT, int Cin, int Cout, int i) {
    int co = i % Cout, ci = i / Cout;
    WT[i] = w[co * Cin + ci];
}

__global__ void pack_all(const float* __restrict__ a1wA, const float* __restrict__ a2wA,
                         const float* __restrict__ a1wB, const float* __restrict__ a2wB,
                         const float* __restrict__ angwB, const float* __restrict__ W1,
                         const float* __restrict__ W2, const float* __restrict__ W3,
                         const float* __restrict__ W3o, const float* __restrict__ angwA,
                         float* __restrict__ WA1T, float* __restrict__ WA2T,
                         float* __restrict__ WB1T, float* __restrict__ WB2T,
                         float* __restrict__ WBAT,
                         float* __restrict__ W1U, float* __restrict__ W1N,
                         float* __restrict__ W2U, float* __restrict__ W2N,
                         float* __restrict__ W3T, float* __restrict__ W3OT,
                         float* __restrict__ WANGA,
                         float* __restrict__ SACC, unsigned* __restrict__ CNT) {
    int iz = blockIdx.x * 256 + threadIdx.x;
    if (iz < 10 * BN * 256 * 2) SACC[iz] = 0.f;
    if (iz < 10) CNT[iz] = 0u;
    int i = iz;
    const int sA = 4 * CH * CH;   // 65536
    const int sB = 3 * CH * CH;   // 49152
    if (i < sA) { d_packA(a1wA, WA1T, i); return; } i -= sA;
    if (i < sA) { d_packA(a2wA, WA2T, i); return; } i -= sA;
    if (i < sB) { d_packB(a1wB, WB1T, i); return; } i -= sB;
    if (i < sB) { d_packB(a2wB, WB2T, i); return; } i -= sB;
    if (i < sB) { d_packB(angwB, WBAT, i); return; } i -= sB;
    if (i < CH * CH) { d_packUV(W1, W1U, W1N, CH, i); return; } i -= CH * CH;
    if (i < CH * 256) { d_packUV(W2, W2U, W2N, 256, i); return; } i -= CH * 256;
    if (i < 384 * CH) { d_packP(W3, W3T, 384, CH, i); return; } i -= 384 * CH;
    if (i < 512 * CH) { d_packP(W3o, W3OT, 512, CH, i); return; } i -= 512 * CH;
    if (i < 3 * CH) { d_packP(angwA, WANGA, 3, CH, i); return; }
}

// ---------------- features transpose ----------------
__global__ void ftrans_kernel(const float* __restrict__ feats, float* __restrict__ F) {
    int i = blockIdx.x * 256 + threadIdx.x;
    if (i >= BN * CH * NP) return;
    int n = i % NP, c = (i / NP) % CH, b = i / (NP * CH);
    F[(b * NP + n) * CH + c] = feats[i];
}

// ---------------- KNN (R5 form — proven fastest correct: 147us) ----------
__global__ void knn_kernel(const float* __restrict__ coords, int* __restrict__ IDX) {
    int gw = blockIdx.x * 4 + (threadIdx.x >> 6);
    int b = gw / NP;
    int n = gw % NP;
    int lane = threadIdx.x & 63;
    float xn = coords[(b * 2 + 0) * NP + n];
    float yn = coords[(b * 2 + 1) * NP + n];
    float sn = __fadd_rn(__fmul_rn(xn, xn), __fmul_rn(yn, yn));
    ull a[11];
    #pragma unroll
    for (int q = 0; q < 11; q++) a[q] = 0xFFFFFFFFFFFFFFFFULL;
    for (int m = lane; m < NP; m += 64) {
        float xm = coords[(b * 2 + 0) * NP + m];
        float ym = coords[(b * 2 + 1) * NP + m];
        float sm = __fadd_rn(__fmul_rn(xm, xm), __fmul_rn(ym, ym));
        float dot = __fmaf_rn(yn, ym, __fmul_rn(xn, xm));
        float d = __fsub_rn(__fadd_rn(sn, sm), __fmul_rn(2.0f, dot));
        d = fmaxf(d, 1e-12f);
        ull key = ((ull)__float_as_uint(d) << 32) | (unsigned)m;
        if (key < a[10]) {
            a[10] = key;
            #pragma unroll
            for (int q = 10; q > 0; --q)
                if (a[q] < a[q - 1]) { ull t = a[q]; a[q] = a[q - 1]; a[q - 1] = t; }
        }
    }
    for (int r = 0; r < 11; ++r) {
        ull k = a[0];
        ull mk = k;
        #pragma unroll
        for (int off = 1; off < 64; off <<= 1) {
            ull o = shfl_xor_u64(mk, off);
            mk = (o < mk) ? o : mk;
        }
        if (k == mk) {
            #pragma unroll
            for (int q = 0; q < 10; ++q) a[q] = a[q + 1];
            a[10] = 0xFFFFFFFFFFFFFFFFULL;
        }
        if (lane == 0 && r > 0) IDX[(b * NP + n) * KNB + (r - 1)] = (int)(mk & 0xFFFFFFFFu);
    }
}

// ---------------- cos_angle ----------------
__global__ void cosangle_kernel(const float* __restrict__ coords, const int* __restrict__ IDX,
                                float* __restrict__ COSA) {
    int i = blockIdx.x * 256 + threadIdx.x;
    if (i >= BN * NP * KNB) return;
    int n = (i / KNB) % NP, b = i / (KNB * NP);
    int j = clampj(IDX[i]);
    float xc = coords[(b * 2 + 0) * NP + n], yc = coords[(b * 2 + 1) * NP + n];
    float xm = coords[(b * 2 + 0) * NP + j], ym = coords[(b * 2 + 1) * NP + j];
    float dot = xc * xm + yc * ym;
    float na = sqrtf(xc * xc + yc * yc);
    float nb2 = sqrtf(xm * xm + ym * ym);
    COSA[i] = dot / fmaxf(na * nb2, 1e-30f);
}

// ---------------- convA v2: 16 pts/block, 2 pts per pg, bf16 neighbor staging ------
__global__ __launch_bounds__(256) void convA_kernel(const float* __restrict__ Fin,
                             const int* __restrict__ IDX,
                             const float* __restrict__ WT, float* __restrict__ YA,
                             const float* __restrict__ STATS_IN, int slot,
                             float* __restrict__ SACC, unsigned* __restrict__ CNT,
                             float* __restrict__ STATS, int oslot) {
    __shared__ __align__(16) float ctr[CA_PTS][CH];                 // 8 KB
    __shared__ __align__(16) unsigned short nbh[CA_PTS][9][CH];     // 36.9 KB
    __shared__ int jidx[CA_PTS * 9];
    int b = blockIdx.x / (NP / CA_PTS);
    int chunk = blockIdx.x % (NP / CA_PTS);
    int n0 = chunk * CA_PTS;
    int cog = threadIdx.x & 31;
    int pg  = threadIdx.x >> 5;
    const float* SB = (slot >= 0) ? &STATS_IN[((size_t)(slot * BN + b) * 256) * 2] : nullptr;
    if (threadIdx.x < CA_PTS * 9) {
        int n = threadIdx.x / 9, kk = threadIdx.x % 9;
        jidx[threadIdx.x] = clampj(IDX[(b * NP + n0 + n) * KNB + kk]);
    }
    __syncthreads();
    for (int v4 = threadIdx.x; v4 < CA_PTS * 32; v4 += 256) {   // ctr: f32
        int n = v4 >> 5, c4 = v4 & 31;
        float4 x = *(const float4*)&Fin[(size_t)(b * NP + n0 + n) * CH + c4 * 4];
        if (SB) {
            float4 s0 = *(const float4*)&SB[c4 * 8];
            float4 s1 = *(const float4*)&SB[c4 * 8 + 4];
            x.x = fmaxf((x.x - s0.x) * s0.y, 0.f);
            x.y = fmaxf((x.y - s0.z) * s0.w, 0.f);
            x.z = fmaxf((x.z - s1.x) * s1.y, 0.f);
            x.w = fmaxf((x.w - s1.z) * s1.w, 0.f);
        }
        *(float4*)&ctr[n][c4 * 4] = x;
    }
    for (int v4 = threadIdx.x; v4 < CA_PTS * 9 * 32; v4 += 256) {   // nb: bf16
        int n = v4 / 288, rem = v4 % 288, kk = rem >> 5, c4 = rem & 31;
        float4 x = *(const float4*)&Fin[(size_t)(b * NP + jidx[n * 9 + kk]) * CH + c4 * 4];
        if (SB) {
            float4 s0 = *(const float4*)&SB[c4 * 8];
            float4 s1 = *(const float4*)&SB[c4 * 8 + 4];
            x.x = fmaxf((x.x - s0.x) * s0.y, 0.f);
            x.y = fmaxf((x.y - s0.z) * s0.w, 0.f);
            x.z = fmaxf((x.z - s1.x) * s1.y, 0.f);
            x.w = fmaxf((x.w - s1.z) * s1.w, 0.f);
        }
        *(ushort4*)&nbh[n][kk][c4 * 4] = bf4(x);
    }
    __syncthreads();
    const float4* W4 = (const float4*)WT;
    const int p0 = pg * 2, p1 = pg * 2 + 1;
    float4 cacc0, cacc1;
    cacc0.x = cacc0.y = cacc0.z = cacc0.w = 0.f;
    cacc1 = cacc0;
    for (int ci = 0; ci < CH; ci += 4) {
        float4 xa = *(const float4*)&ctr[p0][ci];
        float4 xb = *(const float4*)&ctr[p1][ci];
        #pragma unroll
        for (int u = 0; u < 4; ++u) {
            float4 w = W4[(ci + u) * 32 + cog];
            float fa = ((const float*)&xa)[u];
            float fb = ((const float*)&xb)[u];
            FMA4(cacc0, w, fa); FMA4(cacc1, w, fb);
        }
    }
    float4 t00 = cacc0, t01 = cacc0, t02 = cacc0;
    float4 t10 = cacc1, t11 = cacc1, t12 = cacc1;
    for (int dk = 0; dk < 3; ++dk) {
        const float4* Wd = W4 + (size_t)(1 + dk) * (CH * 32);
        const unsigned short* a00 = &nbh[p0][0 * 3 + dk][0];
        const unsigned short* a01 = &nbh[p0][1 * 3 + dk][0];
        const unsigned short* a02 = &nbh[p0][2 * 3 + dk][0];
        const unsigned short* a10 = &nbh[p1][0 * 3 + dk][0];
        const unsigned short* a11 = &nbh[p1][1 * 3 + dk][0];
        const unsigned short* a12 = &nbh[p1][2 * 3 + dk][0];
        for (int ci = 0; ci < CH; ci += 4) {
            float4 x00 = bfload4(&a00[ci]);
            float4 x01 = bfload4(&a01[ci]);
            float4 x02 = bfload4(&a02[ci]);
            float4 x10 = bfload4(&a10[ci]);
            float4 x11 = bfload4(&a11[ci]);
            float4 x12 = bfload4(&a12[ci]);
            #pragma unroll
            for (int u = 0; u < 4; ++u) {
                float4 w = Wd[(ci + u) * 32 + cog];
                FMA4(t00, w, ((const float*)&x00)[u]);
                FMA4(t01, w, ((const float*)&x01)[u]);
                FMA4(t02, w, ((const float*)&x02)[u]);
                FMA4(t10, w, ((const float*)&x10)[u]);
                FMA4(t11, w, ((const float*)&x11)[u]);
                FMA4(t12, w, ((const float*)&x12)[u]);
            }
        }
    }
    {
        size_t base0 = ((size_t)(b * NP + n0 + p0) * 3) * CH + cog * 4;
        *(float4*)&YA[base0 + 0 * CH] = t00;
        *(float4*)&YA[base0 + 1 * CH] = t01;
        *(float4*)&YA[base0 + 2 * CH] = t02;
        size_t base1 = ((size_t)(b * NP + n0 + p1) * 3) * CH + cog * 4;
        *(float4*)&YA[base1 + 0 * CH] = t10;
        *(float4*)&YA[base1 + 1 * CH] = t11;
        *(float4*)&YA[base1 + 2 * CH] = t12;
    }
    float s4[4], q4[4];
    s4[0] = t00.x + t01.x + t02.x + t10.x + t11.x + t12.x;
    s4[1] = t00.y + t01.y + t02.y + t10.y + t11.y + t12.y;
    s4[2] = t00.z + t01.z + t02.z + t10.z + t11.z + t12.z;
    s4[3] = t00.w + t01.w + t02.w + t10.w + t11.w + t12.w;
    q4[0] = t00.x*t00.x + t01.x*t01.x + t02.x*t02.x + t10.x*t10.x + t11.x*t11.x + t12.x*t12.x;
    q4[1] = t00.y*t00.y + t01.y*t01.y + t02.y*t02.y + t10.y*t10.y + t11.y*t11.y + t12.y*t12.y;
    q4[2] = t00.z*t00.z + t01.z*t01.z + t02.z*t02.z + t10.z*t10.z + t11.z*t11.z + t12.z*t12.z;
    q4[3] = t00.w*t00.w + t01.w*t01.w + t02.w*t02.w + t10.w*t10.w + t11.w*t11.w + t12.w*t12.w;
    __syncthreads();                 // nbh reads done -> reuse as reduction buffer
    float* red = (float*)&nbh[0][0][0];
    #pragma unroll
    for (int j = 0; j < 4; ++j) {
        red[((pg * 32 + cog) * 4 + j) * 2 + 0] = s4[j];
        red[((pg * 32 + cog) * 4 + j) * 2 + 1] = q4[j];
    }
    __syncthreads();
    float ss = 0.f, qq = 0.f;
    int c = threadIdx.x;
    int valid = (c < CH);
    if (valid) {
        #pragma unroll
        for (int g = 0; g < 8; ++g) {
            ss += red[((g * 32 + (c >> 2)) * 4 + (c & 3)) * 2 + 0];
            qq += red[((g * 32 + (c >> 2)) * 4 + (c & 3)) * 2 + 1];
        }
    }
    stats_commit(SACC, CNT, STATS, oslot, b, c, valid, ss, qq,
                 BN * (NP / CA_PTS), 3.0f * NP);
}

// ---------------- angle convA (fused stats, oslot=2) ----------------
__global__ void angA_kernel(const float* __restrict__ COSA, const float* __restrict__ WT,
                            float* __restrict__ YA,
                            float* __restrict__ SACC, unsigned* __restrict__ CNT,
                            float* __restrict__ STATS) {
    __shared__ float ca[32][10];
    int b = blockIdx.x / (NP / 32);
    int chunk = blockIdx.x % (NP / 32);
    int n0 = chunk * 32;
    int co = threadIdx.x;
    for (int v = threadIdx.x; v < 320; v += 128) {
        int nn = v / 10, kk = v % 10;
        ca[nn][kk] = COSA[(b * NP + n0 + nn) * KNB + kk];
    }
    float w0 = WT[co], w1 = WT[CH + co], w2 = WT[2 * CH + co];
    __syncthreads();
    float sum = 0.f, sq = 0.f;
    for (int nn = 0; nn < 32; nn++) {
        #pragma unroll
        for (int t = 0; t < 3; t++) {
            float v = w0 * ca[nn][3 * t] + w1 * ca[nn][3 * t + 1] + w2 * ca[nn][3 * t + 2];
            YA[((b * NP + n0 + nn) * 3 + t) * CH + co] = v;
            sum += v; sq += v * v;
        }
    }
    stats_commit(SACC, CNT, STATS, 2, b, co, 1, sum, sq, BN * (NP / 32), 3.0f * NP);
}

// ---------------- shared GEMM core: 16 pts/block, 4 co/thread ----------------
template <int CIN, int NCOG>
__device__ __forceinline__ void gemm_16pt(const float* lds, const float* __restrict__ WT,
                                          int cog, int pg, float4 acc[4]) {
    const float4* W4 = (const float4*)WT;
    const float* xb = lds + pg * 4 * CIN;
    for (int ci = 0; ci < CIN; ci += 4) {
        float4 x0 = *(const float4*)&xb[0 * CIN + ci];
        float4 x1 = *(const float4*)&xb[1 * CIN + ci];
        float4 x2 = *(const float4*)&xb[2 * CIN + ci];
        float4 x3 = *(const float4*)&xb[3 * CIN + ci];
        #pragma unroll
        for (int u = 0; u < 4; ++u) {
            float4 w = W4[(ci + u) * NCOG + cog];
            float f0 = ((const float*)&x0)[u];
            float f1 = ((const float*)&x1)[u];
            float f2 = ((const float*)&x2)[u];
            float f3 = ((const float*)&x3)[u];
            FMA4(acc[0], w, f0); FMA4(acc[1], w, f1);
            FMA4(acc[2], w, f2); FMA4(acc[3], w, f3);
        }
    }
}

// tree-combine across pgs in LDS, then fused atomic commit
template <int NCOG>
__device__ __forceinline__ void reduce_commit(const float* s4, const float* q4,
                                              float* red,
                                              float* __restrict__ SACC,
                                              unsigned* __restrict__ CNT,
                                              float* __restrict__ STATS,
                                              int oslot, int b, int nblk, float Sdiv,
                                              int pg, int cog) {
    constexpr int COUT = NCOG * 4;
    __syncthreads();
    #pragma unroll
    for (int j = 0; j < 4; ++j) {
        red[((pg * NCOG + cog) * 4 + j) * 2 + 0] = s4[j];
        red[((pg * NCOG + cog) * 4 + j) * 2 + 1] = q4[j];
    }
    __syncthreads();
    int c = threadIdx.x;
    float ss = 0.f, qq = 0.f;
    int valid = (c < COUT);
    if (valid) {
        #pragma unroll
        for (int g = 0; g < 4; ++g) {
            ss += red[((g * NCOG + (c >> 2)) * 4 + (c & 3)) * 2 + 0];
            qq += red[((g * NCOG + (c >> 2)) * 4 + (c & 3)) * 2 + 1];
        }
    }
    stats_commit(SACC, CNT, STATS, oslot, b, c, valid, ss, qq, nblk, Sdiv);
}

// out + per-channel partial-stat accumulation for the 16-pt kernels
template <int NCOG>
__device__ __forceinline__ void out16(const float4 acc[4], float* __restrict__ OUT,
                                      int b, int n0, int pg, int cog,
                                      float s4[4], float q4[4]) {
    constexpr int COUT = NCOG * 4;
    #pragma unroll
    for (int p = 0; p < 4; ++p) {
        *(float4*)&OUT[(size_t)(b * NP + n0 + pg * 4 + p) * COUT + cog * 4] = acc[p];
        s4[0] += acc[p].x; s4[1] += acc[p].y; s4[2] += acc[p].z; s4[3] += acc[p].w;
        q4[0] += acc[p].x * acc[p].x; q4[1] += acc[p].y * acc[p].y;
        q4[2] += acc[p].z * acc[p].z; q4[3] += acc[p].w * acc[p].w;
    }
}

// ---------------- per-pixel GEMM: fused input norm+act, fused output stats ----------
template <int CIN, int NCOG>
__global__ void pixel_gemm_t(const float* __restrict__ IN_, const float* __restrict__ WT,
                             float* __restrict__ OUT, const float* __restrict__ STATS_IN,
                             int slot, int act,
                             float* __restrict__ SACC, unsigned* __restrict__ CNT,
                             float* __restrict__ STATS, int oslot) {
    constexpr int COUT = NCOG * 4;
    constexpr int BD = 4 * NCOG;
    __shared__ __align__(16) float ldsin[16 * CIN];
    int b = blockIdx.x / (NP / 16);
    int chunk = blockIdx.x % (NP / 16);
    int n0 = chunk * 16;
    int cog = threadIdx.x & (NCOG - 1);
    int pg = threadIdx.x / NCOG;
    constexpr int nv4 = 16 * CIN / 4;
    if (slot >= 0) {
        int cbase = (4 * threadIdx.x) & 127;     // channel set is constant per thread
        const float* st = &STATS_IN[((slot * BN + b) * 256 + cbase) * 2];
        float m0 = st[0], r0 = st[1], m1 = st[2], r1 = st[3];
        float m2 = st[4], r2 = st[5], m3 = st[6], r3 = st[7];
        for (int v4 = threadIdx.x; v4 < nv4; v4 += BD) {
            float4 x = *(const float4*)&IN_[(size_t)(b * NP + n0) * CIN + 4 * v4];
            float v0 = (x.x - m0) * r0, v1 = (x.y - m1) * r1;
            float v2 = (x.z - m2) * r2, v3 = (x.w - m3) * r3;
            if (act) {
                x.x = (v0 >= 0.f) ? v0 : 0.2f * v0;
                x.y = (v1 >= 0.f) ? v1 : 0.2f * v1;
                x.z = (v2 >= 0.f) ? v2 : 0.2f * v2;
                x.w = (v3 >= 0.f) ? v3 : 0.2f * v3;
            } else {
                x.x = fmaxf(v0, 0.f); x.y = fmaxf(v1, 0.f);
                x.z = fmaxf(v2, 0.f); x.w = fmaxf(v3, 0.f);
            }
            *(float4*)&ldsin[4 * v4] = x;
        }
    } else {
        for (int v4 = threadIdx.x; v4 < nv4; v4 += BD)
            *(float4*)&ldsin[4 * v4] =
                *(const float4*)&IN_[(size_t)(b * NP + n0) * CIN + 4 * v4];
    }
    __syncthreads();
    float4 acc[4];
    #pragma unroll
    for (int p = 0; p < 4; ++p) acc[p].x = acc[p].y = acc[p].z = acc[p].w = 0.f;
    gemm_16pt<CIN, NCOG>(ldsin, WT, cog, pg, acc);
    float s4[4] = {0,0,0,0}, q4[4] = {0,0,0,0};
    out16<NCOG>(acc, OUT, b, n0, pg, cog, s4, q4);
    if (oslot >= 0)
        reduce_commit<NCOG>(s4, q4, ldsin, SACC, CNT, STATS, oslot, b,
                            BN * (NP / 16), (float)NP, pg, cog);
}

// ---------------- fused U-GEMM + gather + max + fused stats ----------------
template <int NCOG>
__global__ void gathermax_t(const float* __restrict__ X, const float* __restrict__ Wu,
                            const float* __restrict__ V, const int* __restrict__ IDX,
                            float* __restrict__ M, const float* __restrict__ STATS_IN,
                            int slot,
                            float* __restrict__ SACC, unsigned* __restrict__ CNT,
                            float* __restrict__ STATS, int oslot) {
    constexpr int COUT = NCOG * 4;
    __shared__ __align__(16) float rows[GM_PTS * CH];
    int b = blockIdx.x / (NP / GM_PTS);
    int chunk = blockIdx.x % (NP / GM_PTS);
    int n0 = chunk * GM_PTS;
    int cog = threadIdx.x & (NCOG - 1);
    int pg = threadIdx.x / NCOG;
    if (slot >= 0) {
        int c0 = (4 * threadIdx.x) & 127;     // fixed channel set per thread
        const float* st = &STATS_IN[((slot * BN + b) * 256 + c0) * 2];
        float m0 = st[0], r0 = st[1], m1 = st[2], r1 = st[3];
        float m2 = st[4], r2 = st[5], m3 = st[6], r3 = st[7];
        for (int v4 = threadIdx.x; v4 < GM_PTS * CH / 4; v4 += COUT) {
            float4 x = *(const float4*)&X[(size_t)(b * NP + n0) * CH + v4 * 4];
            float v0 = (x.x - m0) * r0, v1 = (x.y - m1) * r1;
            float v2 = (x.z - m2) * r2, v3 = (x.w - m3) * r3;
            x.x = (v0 >= 0.f) ? v0 : 0.2f * v0;
            x.y = (v1 >= 0.f) ? v1 : 0.2f * v1;
            x.z = (v2 >= 0.f) ? v2 : 0.2f * v2;
            x.w = (v3 >= 0.f) ? v3 : 0.2f * v3;
            *(float4*)&rows[v4 * 4] = x;
        }
    } else {
        for (int v4 = threadIdx.x; v4 < GM_PTS * CH / 4; v4 += COUT)
            *(float4*)&rows[v4 * 4] = *(const float4*)&X[(size_t)(b * NP + n0) * CH + v4 * 4];
    }
    __syncthreads();
    float4 acc[4];
    #pragma unroll
    for (int p = 0; p < 4; ++p) acc[p].x = acc[p].y = acc[p].z = acc[p].w = 0.f;
    gemm_16pt<CH, NCOG>(rows, Wu, cog, pg, acc);
    float s4[4] = {0,0,0,0}, q4[4] = {0,0,0,0};
    #pragma unroll
    for (int p = 0; p < 4; ++p) {
        int nn = n0 + pg * 4 + p;
        float4 u = acc[p];
        float4 best; best.x = best.y = best.z = best.w = -3.4e38f;
        for (int k = 0; k < KNB; ++k) {
            int j = clampj(IDX[(b * NP + nn) * KNB + k]);
            float4 vv = *(const float4*)&V[(size_t)(b * NP + j) * COUT + cog * 4];
            vv.x += u.x; vv.y += u.y; vv.z += u.z; vv.w += u.w;
            s4[0] += vv.x; s4[1] += vv.y; s4[2] += vv.z; s4[3] += vv.w;
            q4[0] += vv.x * vv.x; q4[1] += vv.y * vv.y;
            q4[2] += vv.z * vv.z; q4[3] += vv.w * vv.w;
            best.x = fmaxf(best.x, vv.x); best.y = fmaxf(best.y, vv.y);
            best.z = fmaxf(best.z, vv.z); best.w = fmaxf(best.w, vv.w);
        }
        *(float4*)&M[(size_t)(b * NP + nn) * COUT + cog * 4] = best;
    }
    __syncthreads();   // rows no longer needed
    reduce_commit<NCOG>(s4, q4, rows, SACC, CNT, STATS, oslot, b,
                        BN * (NP / GM_PTS), (float)(NP * KNB), pg, cog);
}

// ---------------- heads (fused input norms + fused output stats) ----------------
__global__ void head3_kernel(const float* __restrict__ F, const float* __restrict__ X1,
                             const float* __restrict__ X2, const float* __restrict__ FANG,
                             const float* __restrict__ WT, float* __restrict__ Y3,
                             const float* __restrict__ STATS_IN,
                             float* __restrict__ SACC, unsigned* __restrict__ CNT,
                             float* __restrict__ STATS) {
    __shared__ __align__(16) float lds[16 * 384];
    int b = blockIdx.x / (NP / 16);
    int chunk = blockIdx.x % (NP / 16);
    int n0 = chunk * 16;
    int cog = threadIdx.x & 31;
    int pg = threadIdx.x >> 5;
    const float* S1 = &STATS_IN[((size_t)(1 * BN + b) * 256) * 2];
    const float* S5 = &STATS_IN[((size_t)(5 * BN + b) * 256) * 2];
    const float* S3 = &STATS_IN[((size_t)(3 * BN + b) * 256) * 2];
    for (int v4 = threadIdx.x; v4 < 16 * 96; v4 += 128) {
        int nn = v4 / 96, q4 = v4 % 96;
        int part = q4 >> 5, c4 = q4 & 31;
        size_t base = (size_t)(b * NP + n0 + nn) * CH + c4 * 4;
        float4 val;
        if (part == 0) val = *(const float4*)&F[base];
        else {
            const float* src = (part == 1) ? X1 : X2;
            const float* SX = (part == 1) ? S1 : S5;
            float4 xx = *(const float4*)&src[base];
            float4 aa = *(const float4*)&FANG[base];
            float4 sx0 = *(const float4*)&SX[c4 * 8];
            float4 sx1 = *(const float4*)&SX[c4 * 8 + 4];
            float4 sa0 = *(const float4*)&S3[c4 * 8];
            float4 sa1 = *(const float4*)&S3[c4 * 8 + 4];
            val.x = fmaxf((xx.x - sx0.x) * sx0.y, 0.f) + fmaxf((aa.x - sa0.x) * sa0.y, 0.f);
            val.y = fmaxf((xx.y - sx0.z) * sx0.w, 0.f) + fmaxf((aa.y - sa0.z) * sa0.w, 0.f);
            val.z = fmaxf((xx.z - sx1.x) * sx1.y, 0.f) + fmaxf((aa.z - sa1.x) * sa1.y, 0.f);
            val.w = fmaxf((xx.w - sx1.z) * sx1.w, 0.f) + fmaxf((aa.w - sa1.z) * sa1.w, 0.f);
        }
        *(float4*)&lds[v4 * 4] = val;
    }
    __syncthreads();
    float4 acc[4];
    #pragma unroll
    for (int p = 0; p < 4; ++p) acc[p].x = acc[p].y = acc[p].z = acc[p].w = 0.f;
    gemm_16pt<384, 32>(lds, WT, cog, pg, acc);
    float s4[4] = {0,0,0,0}, q4[4] = {0,0,0,0};
    out16<32>(acc, Y3, b, n0, pg, cog, s4, q4);
    reduce_commit<32>(s4, q4, lds, SACC, CNT, STATS, 8, b,
                      BN * (NP / 16), (float)NP, pg, cog);
}

__global__ void head3o_kernel(const float* __restrict__ F, const float* __restrict__ X1O,
                              const float* __restrict__ X2O, const float* __restrict__ WT,
                              float* __restrict__ Y3O, const float* __restrict__ STATS_IN,
                              float* __restrict__ SACC, unsigned* __restrict__ CNT,
                              float* __restrict__ STATS) {
    __shared__ __align__(16) float lds[16 * 512];
    int b = blockIdx.x / (NP / 16);
    int chunk = blockIdx.x % (NP / 16);
    int n0 = chunk * 16;
    int cog = threadIdx.x & 31;
    int pg = threadIdx.x >> 5;
    const float* S6 = &STATS_IN[((size_t)(6 * BN + b) * 256) * 2];
    const float* S7 = &STATS_IN[((size_t)(7 * BN + b) * 256) * 2];
    for (int v4 = threadIdx.x; v4 < 16 * 128; v4 += 128) {
        int nn = v4 >> 7, q4 = v4 & 127;
        float4 val;
        if (q4 < 32) {
            val = *(const float4*)&F[(size_t)(b * NP + n0 + nn) * CH + q4 * 4];
        } else if (q4 < 64) {
            int c4 = q4 - 32;
            float4 x = *(const float4*)&X1O[(size_t)(b * NP + n0 + nn) * CH + c4 * 4];
            float4 s0 = *(const float4*)&S6[c4 * 8];
            float4 s1 = *(const float4*)&S6[c4 * 8 + 4];
            float v0 = (x.x - s0.x) * s0.y, v1 = (x.y - s0.z) * s0.w;
            float v2 = (x.z - s1.x) * s1.y, v3 = (x.w - s1.z) * s1.w;
            val.x = (v0 >= 0.f) ? v0 : 0.2f * v0;
            val.y = (v1 >= 0.f) ? v1 : 0.2f * v1;
            val.z = (v2 >= 0.f) ? v2 : 0.2f * v2;
            val.w = (v3 >= 0.f) ? v3 : 0.2f * v3;
        } else {
            int c4 = q4 - 64;   // channels 0..255
            float4 x = *(const float4*)&X2O[(size_t)(b * NP + n0 + nn) * 256 + c4 * 4];
            float4 s0 = *(const float4*)&S7[c4 * 8];
            float4 s1 = *(const float4*)&S7[c4 * 8 + 4];
            float v0 = (x.x - s0.x) * s0.y, v1 = (x.y - s0.z) * s0.w;
            float v2 = (x.z - s1.x) * s1.y, v3 = (x.w - s1.z) * s1.w;
            val.x = (v0 >= 0.f) ? v0 : 0.2f * v0;
            val.y = (v1 >= 0.f) ? v1 : 0.2f * v1;
            val.z = (v2 >= 0.f) ? v2 : 0.2f * v2;
            val.w = (v3 >= 0.f) ? v3 : 0.2f * v3;
        }
        *(float4*)&lds[v4 * 4] = val;
    }
    __syncthreads();
    float4 acc[4];
    #pragma unroll
    for (int p = 0; p < 4; ++p) acc[p].x = acc[p].y = acc[p].z = acc[p].w = 0.f;
    gemm_16pt<512, 32>(lds, WT, cog, pg, acc);
    float s4[4] = {0,0,0,0}, q4[4] = {0,0,0,0};
    out16<32>(acc, Y3O, b, n0, pg, cog, s4, q4);
    reduce_commit<32>(s4, q4, lds, SACC, CNT, STATS, 9, b,
                      BN * (NP / 16), (float)NP, pg, cog);
}

// ---------------- final ----------------
__global__ void final_kernel(const float* __restrict__ Y3, const float* __restrict__ Y3O,
                             const float* __restrict__ STATS, float* __restrict__ out) {
    __shared__ float T[64][129];
    int b = blockIdx.x / (NP / 64);
    int n0 = (blockIdx.x % (NP / 64)) * 64;
    int co = threadIdx.x;
    float m3 = STATS[((8 * BN + b) * 256 + co) * 2 + 0];
    float r3 = STATS[((8 * BN + b) * 256 + co) * 2 + 1];
    float m3o = STATS[((9 * BN + b) * 256 + co) * 2 + 0];
    float r3o = STATS[((9 * BN + b) * 256 + co) * 2 + 1];
    for (int j = 0; j < 64; j++) {
        size_t idx = (size_t)(b * NP + n0 + j) * CH + co;
        float v3 = (Y3[idx] - m3) * r3;
        v3 = (v3 >= 0.f) ? v3 : 0.2f * v3;
        float v3o = (Y3O[idx] - m3o) * r3o;
        v3o = (v3o >= 0.f) ? v3o : 0.2f * v3o;
        T[j][co] = v3 + v3o;
    }
    __syncthreads();
    for (int rr = 0; rr < 64; rr++) {
        int r = rr * 2 + (threadIdx.x >> 6);
        int j = threadIdx.x & 63;
        out[(size_t)(b * CH + r) * NP + n0 + j] = T[j][r];
    }
}

// ---------------- launch ----------------
extern "C" void kernel_launch(void* const* d_in, const int* in_sizes, int n_in,
                              void* d_out, int out_size, void* d_ws, size_t ws_size,
                              hipStream_t stream) {
    const float* coords   = (const float*)d_in[0];
    const float* features = (const float*)d_in[1];
    const float* W1   = (const float*)d_in[2];
    const float* W2   = (const float*)d_in[3];
    const float* W3   = (const float*)d_in[4];
    const float* W3o  = (const float*)d_in[5];
    const float* a1wA = (const float*)d_in[6];
    const float* a1wB = (const float*)d_in[8];
    const float* a2wA = (const float*)d_in[10];
    const float* a2wB = (const float*)d_in[12];
    const float* angwA = (const float*)d_in[14];
    const float* angwB = (const float*)d_in[16];
    float* out = (float*)d_out;
    float* ws = (float*)d_ws;
    (void)ws_size; (void)in_sizes; (void)n_in; (void)out_size;

    size_t off = 0;
    float* WA1T  = ws + off; off += 4 * CH * CH;
    float* WA2T  = ws + off; off += 4 * CH * CH;
    float* WB1T  = ws + off; off += 3 * CH * CH;
    float* WB2T  = ws + off; off += 3 * CH * CH;
    float* WBAT  = ws + off; off += 3 * CH * CH;
    float* WANGA = ws + off; off += 512;
    float* W1U   = ws + off; off += CH * CH;
    float* W1N   = ws + off; off += CH * CH;
    float* W2U   = ws + off; off += CH * 256;
    float* W2N   = ws + off; off += CH * 256;
    float* W3T   = ws + off; off += 384 * CH;
    float* W3OT  = ws + off; off += 512 * CH;
    int*   IDX   = (int*)(ws + off); off += (size_t)BN * NP * KNB;
    float* COSA  = ws + off; off += (size_t)BN * NP * KNB;
    float* PART  = ws + off; off += (size_t)BN * 1024 * 256 * 2;
    float* STATS = ws + off; off += 10 * BN * 256 * 2;
    const size_t UNIT = (size_t)BN * NP * CH;
    float* POOL  = ws + off; off += 7 * UNIT;

    float* F    = POOL + 0 * UNIT;
    float* YA   = POOL + 1 * UNIT;  // slots 1-3
    float* X1   = POOL + 4 * UNIT;
    float* FANG = POOL + 5 * UNIT;
    float* X2   = POOL + 6 * UNIT;
    float* Y3   = POOL + 1 * UNIT;  // slot 1 (YA dead)
    float* V1   = POOL + 2 * UNIT;  // slot 2
    float* M1   = POOL + 6 * UNIT;  // slot 6 (X2 dead)  -> X1O
    float* V2   = POOL + 4 * UNIT;  // slots 4-5 (X1,FANG dead)
    float* M2   = POOL + 2 * UNIT;  // slots 2-3 (V1 dead) -> X2O
    float* Y3O  = POOL + 4 * UNIT;  // slot 4 (V2 dead)

    // Fused-stats accumulators live in PART's DEAD upper region (PART provisioned
    // for nch=1024 but max nch ever used was 256 -> floats [524288, 2097152) free).
    // SACC at +4MB (float offset 1<<20): 20480 floats; CNT right after: 10 u32.
    float* SACC = PART + (1 << 20);
    unsigned* CNT = (unsigned*)(SACC + 10 * BN * 256 * 2);

    pack_all<<<1730, 256, 0, stream>>>(a1wA, a2wA, a1wB, a2wB, angwB, W1, W2, W3, W3o, angwA,
                                       WA1T, WA2T, WB1T, WB2T, WBAT,
                                       W1U, W1N, W2U, W2N, W3T, W3OT, WANGA,
                                       SACC, CNT);

    ftrans_kernel<<<(BN * CH * NP + 255) / 256, 256, 0, stream>>>(features, F);
    knn_kernel<<<BN * NP / 4, 256, 0, stream>>>(coords, IDX);
    cosangle_kernel<<<(BN * NP * KNB + 255) / 256, 256, 0, stream>>>(coords, IDX, COSA);

    // --- x1 block ---
    convA_kernel<<<BN * (NP / CA_PTS), 256, 0, stream>>>(F, IDX, WA1T, YA, STATS, -1,
                                                         SACC, CNT, STATS, 0);
    pixel_gemm_t<384, 32><<<BN * (NP / 16), 128, 0, stream>>>(YA, WB1T, X1, STATS, 0, 0,
                                                              SACC, CNT, STATS, 1);

    // --- angle block ---
    angA_kernel<<<BN * (NP / 32), 128, 0, stream>>>(COSA, WANGA, YA, SACC, CNT, STATS);
    pixel_gemm_t<384, 32><<<BN * (NP / 16), 128, 0, stream>>>(YA, WBAT, FANG, STATS, 2, 0,
                                                              SACC, CNT, STATS, 3);

    // --- x2 block (convA applies relu-norm slot1 to X1) ---
    convA_kernel<<<BN * (NP / CA_PTS), 256, 0, stream>>>(X1, IDX, WA2T, YA, STATS, 1,
                                                         SACC, CNT, STATS, 4);
    pixel_gemm_t<384, 32><<<BN * (NP / 16), 128, 0, stream>>>(YA, WB2T, X2, STATS, 4, 0,
                                                              SACC, CNT, STATS, 5);

    // --- head3 (fuses relu-norm of X1/X2/FANG, slots 1/5/3) ---
    head3_kernel<<<BN * (NP / 16), 128, 0, stream>>>(F, X1, X2, FANG, W3T, Y3, STATS,
                                                     SACC, CNT, STATS);

    // --- x1o path ---
    pixel_gemm_t<128, 32><<<BN * (NP / 16), 128, 0, stream>>>(F, W1N, V1, STATS, -1, 0,
                                                              SACC, CNT, STATS, -1);
    gathermax_t<32><<<BN * (NP / GM_PTS), 128, 0, stream>>>(F, W1U, V1, IDX, M1, STATS, -1,
                                                            SACC, CNT, STATS, 6);

    // --- x2o path (consumers apply leaky-norm slot6 to M1) ---
    pixel_gemm_t<128, 64><<<BN * (NP / 16), 256, 0, stream>>>(M1, W2N, V2, STATS, 6, 1,
                                                              SACC, CNT, STATS, -1);
    gathermax_t<64><<<BN * (NP / GM_PTS), 256, 0, stream>>>(M1, W2U, V2, IDX, M2, STATS, 6,
                                                            SACC, CNT, STATS, 7);

    // --- head3o (fuses leaky-norm of M1/M2, slots 6/7) + final ---
    head3o_kernel<<<BN * (NP / 16), 128, 0, stream>>>(F, M1, M2, W3OT, Y3O, STATS,
                                                      SACC, CNT, STATS);
    final_kernel<<<BN * (NP / 64), 128, 0, stream>>>(Y3, Y3O, STATS, out);
}

// Round 17
// 840.637 us; speedup vs baseline: 1.3624x; 1.3624x over previous
//
#include <hip/hip_runtime.h>
#include <hip/hip_bf16.h>

typedef unsigned long long ull;

#define BN 4
#define CH 128
#define NP 4096
#define KNB 10
#define EPSI 1e-5f
#define GM_PTS 16
#define CA_PTS 16

#define FMA4(A, W, F) do { (A).x += (W).x*(F); (A).y += (W).y*(F); \
                           (A).z += (W).z*(F); (A).w += (W).w*(F); } while(0)

__device__ __forceinline__ ull shfl_xor_u64(ull v, int mask) {
    unsigned lo = (unsigned)(v & 0xFFFFFFFFu);
    unsigned hi = (unsigned)(v >> 32);
    lo = __shfl_xor(lo, mask);
    hi = __shfl_xor(hi, mask);
    return ((ull)hi << 32) | lo;
}

__device__ __forceinline__ int clampj(int j) { return ((unsigned)j < (unsigned)NP) ? j : 0; }

__device__ __forceinline__ unsigned short f2bf(float f) {   // RNE
    unsigned u = __float_as_uint(f);
    unsigned r = u + 0x7FFFu + ((u >> 16) & 1u);
    return (unsigned short)(r >> 16);
}
__device__ __forceinline__ float bf2f(unsigned short h) {
    return __uint_as_float(((unsigned)h) << 16);
}
__device__ __forceinline__ float4 bfload4(const unsigned short* p) {
    ushort4 h = *(const ushort4*)p;
    float4 r; r.x = bf2f(h.x); r.y = bf2f(h.y); r.z = bf2f(h.z); r.w = bf2f(h.w);
    return r;
}
__device__ __forceinline__ ushort4 bf4(float4 x) {
    ushort4 h; h.x = f2bf(x.x); h.y = f2bf(x.y); h.z = f2bf(x.z); h.w = f2bf(x.w);
    return h;
}

// ---------------- weight packing (all 10 packs in ONE launch) ----------------
__device__ __forceinline__ void d_packA(const float* w, float* WT, int i) {
    int co = i % CH, ci = (i / CH) % CH, s = i / (CH * CH);
    float val;
    if (s == 0) {
        val = 0.f;
        for (int dk = 0; dk < 3; dk++)
            val += w[(co * 256 + ci) * 3 + dk] - w[(co * 256 + 128 + ci) * 3 + dk];
    } else {
        val = w[(co * 256 + 128 + ci) * 3 + (s - 1)];
    }
    WT[i] = val;
}
__device__ __forceinline__ void d_packB(const float* w, float* WT, int i) {
    int co = i % CH, ci = (i / CH) % CH, dk = i / (CH * CH);
    WT[i] = w[(co * CH + ci) * 3 + dk];
}
__device__ __forceinline__ void d_packUV(const float* w, float* Wu, float* Wn, int Cout, int i) {
    int co = i % Cout, ci = i / Cout;
    float a = w[co * 256 + ci], bb = w[co * 256 + 128 + ci];
    Wu[i] = a - bb; Wn[i] = bb;
}
__device__ __forceinline__ void d_packP(const float* w, float* WT, int Cin, int Cout, int i) {
    int co = i % Cout, ci = i / Cout;
    WT[i] = w[co * Cin + ci];
}

__global__ void pack_all(const float* __restrict__ a1wA, const float* __restrict__ a2wA,
                         const float* __restrict__ a1wB, const float* __restrict__ a2wB,
                         const float* __restrict__ angwB, const float* __restrict__ W1,
                         const float* __restrict__ W2, const float* __restrict__ W3,
                         const float* __restrict__ W3o, const float* __restrict__ angwA,
                         float* __restrict__ WA1T, float* __restrict__ WA2T,
                         float* __restrict__ WB1T, float* __restrict__ WB2T,
                         float* __restrict__ WBAT,
                         float* __restrict__ W1U, float* __restrict__ W1N,
                         float* __restrict__ W2U, float* __restrict__ W2N,
                         float* __restrict__ W3T, float* __restrict__ W3OT,
                         float* __restrict__ WANGA) {
    int i = blockIdx.x * 256 + threadIdx.x;
    const int sA = 4 * CH * CH;   // 65536
    const int sB = 3 * CH * CH;   // 49152
    if (i < sA) { d_packA(a1wA, WA1T, i); return; } i -= sA;
    if (i < sA) { d_packA(a2wA, WA2T, i); return; } i -= sA;
    if (i < sB) { d_packB(a1wB, WB1T, i); return; } i -= sB;
    if (i < sB) { d_packB(a2wB, WB2T, i); return; } i -= sB;
    if (i < sB) { d_packB(angwB, WBAT, i); return; } i -= sB;
    if (i < CH * CH) { d_packUV(W1, W1U, W1N, CH, i); return; } i -= CH * CH;
    if (i < CH * 256) { d_packUV(W2, W2U, W2N, 256, i); return; } i -= CH * 256;
    if (i < 384 * CH) { d_packP(W3, W3T, 384, CH, i); return; } i -= 384 * CH;
    if (i < 512 * CH) { d_packP(W3o, W3OT, 512, CH, i); return; } i -= 512 * CH;
    if (i < 3 * CH) { d_packP(angwA, WANGA, 3, CH, i); return; }
}

// ---------------- features transpose ----------------
__global__ void ftrans_kernel(const float* __restrict__ feats, float* __restrict__ F) {
    int i = blockIdx.x * 256 + threadIdx.x;
    if (i >= BN * CH * NP) return;
    int n = i % NP, c = (i / NP) % CH, b = i / (NP * CH);
    F[(b * NP + n) * CH + c] = feats[i];
}

// ---------------- KNN (R5 form — proven fastest correct: 147us) ----------
__global__ void knn_kernel(const float* __restrict__ coords, int* __restrict__ IDX) {
    int gw = blockIdx.x * 4 + (threadIdx.x >> 6);
    int b = gw / NP;
    int n = gw % NP;
    int lane = threadIdx.x & 63;
    float xn = coords[(b * 2 + 0) * NP + n];
    float yn = coords[(b * 2 + 1) * NP + n];
    float sn = __fadd_rn(__fmul_rn(xn, xn), __fmul_rn(yn, yn));
    ull a[11];
    #pragma unroll
    for (int q = 0; q < 11; q++) a[q] = 0xFFFFFFFFFFFFFFFFULL;
    for (int m = lane; m < NP; m += 64) {
        float xm = coords[(b * 2 + 0) * NP + m];
        float ym = coords[(b * 2 + 1) * NP + m];
        float sm = __fadd_rn(__fmul_rn(xm, xm), __fmul_rn(ym, ym));
        float dot = __fmaf_rn(yn, ym, __fmul_rn(xn, xm));
        float d = __fsub_rn(__fadd_rn(sn, sm), __fmul_rn(2.0f, dot));
        d = fmaxf(d, 1e-12f);
        ull key = ((ull)__float_as_uint(d) << 32) | (unsigned)m;
        if (key < a[10]) {
            a[10] = key;
            #pragma unroll
            for (int q = 10; q > 0; --q)
                if (a[q] < a[q - 1]) { ull t = a[q]; a[q] = a[q - 1]; a[q - 1] = t; }
        }
    }
    for (int r = 0; r < 11; ++r) {
        ull k = a[0];
        ull mk = k;
        #pragma unroll
        for (int off = 1; off < 64; off <<= 1) {
            ull o = shfl_xor_u64(mk, off);
            mk = (o < mk) ? o : mk;
        }
        if (k == mk) {
            #pragma unroll
            for (int q = 0; q < 10; ++q) a[q] = a[q + 1];
            a[10] = 0xFFFFFFFFFFFFFFFFULL;
        }
        if (lane == 0 && r > 0) IDX[(b * NP + n) * KNB + (r - 1)] = (int)(mk & 0xFFFFFFFFu);
    }
}

// ---------------- cos_angle ----------------
__global__ void cosangle_kernel(const float* __restrict__ coords, const int* __restrict__ IDX,
                                float* __restrict__ COSA) {
    int i = blockIdx.x * 256 + threadIdx.x;
    if (i >= BN * NP * KNB) return;
    int n = (i / KNB) % NP, b = i / (KNB * NP);
    int j = clampj(IDX[i]);
    float xc = coords[(b * 2 + 0) * NP + n], yc = coords[(b * 2 + 1) * NP + n];
    float xm = coords[(b * 2 + 0) * NP + j], ym = coords[(b * 2 + 1) * NP + j];
    float dot = xc * xm + yc * ym;
    float na = sqrtf(xc * xc + yc * yc);
    float nb2 = sqrtf(xm * xm + ym * ym);
    COSA[i] = dot / fmaxf(na * nb2, 1e-30f);
}

// ---------------- convA v2: 16 pts/block, 2 pts per pg, bf16 neighbor staging ------
__global__ __launch_bounds__(256) void convA_kernel(const float* __restrict__ Fin,
                             const int* __restrict__ IDX,
                             const float* __restrict__ WT, float* __restrict__ YA,
                             float* __restrict__ PART,
                             const float* __restrict__ STATS, int slot) {
    __shared__ __align__(16) float ctr[CA_PTS][CH];                 // 8 KB
    __shared__ __align__(16) unsigned short nbh[CA_PTS][9][CH];     // 36.9 KB
    __shared__ int jidx[CA_PTS * 9];
    int b = blockIdx.x / (NP / CA_PTS);
    int chunk = blockIdx.x % (NP / CA_PTS);
    int n0 = chunk * CA_PTS;
    int cog = threadIdx.x & 31;
    int pg  = threadIdx.x >> 5;
    const float* SB = (slot >= 0) ? &STATS[((size_t)(slot * BN + b) * 256) * 2] : nullptr;
    if (threadIdx.x < CA_PTS * 9) {
        int n = threadIdx.x / 9, kk = threadIdx.x % 9;
        jidx[threadIdx.x] = clampj(IDX[(b * NP + n0 + n) * KNB + kk]);
    }
    __syncthreads();
    for (int v4 = threadIdx.x; v4 < CA_PTS * 32; v4 += 256) {   // ctr: f32
        int n = v4 >> 5, c4 = v4 & 31;
        float4 x = *(const float4*)&Fin[(size_t)(b * NP + n0 + n) * CH + c4 * 4];
        if (SB) {
            float4 s0 = *(const float4*)&SB[c4 * 8];
            float4 s1 = *(const float4*)&SB[c4 * 8 + 4];
            x.x = fmaxf((x.x - s0.x) * s0.y, 0.f);
            x.y = fmaxf((x.y - s0.z) * s0.w, 0.f);
            x.z = fmaxf((x.z - s1.x) * s1.y, 0.f);
            x.w = fmaxf((x.w - s1.z) * s1.w, 0.f);
        }
        *(float4*)&ctr[n][c4 * 4] = x;
    }
    for (int v4 = threadIdx.x; v4 < CA_PTS * 9 * 32; v4 += 256) {   // nb: bf16
        int n = v4 / 288, rem = v4 % 288, kk = rem >> 5, c4 = rem & 31;
        float4 x = *(const float4*)&Fin[(size_t)(b * NP + jidx[n * 9 + kk]) * CH + c4 * 4];
        if (SB) {
            float4 s0 = *(const float4*)&SB[c4 * 8];
            float4 s1 = *(const float4*)&SB[c4 * 8 + 4];
            x.x = fmaxf((x.x - s0.x) * s0.y, 0.f);
            x.y = fmaxf((x.y - s0.z) * s0.w, 0.f);
            x.z = fmaxf((x.z - s1.x) * s1.y, 0.f);
            x.w = fmaxf((x.w - s1.z) * s1.w, 0.f);
        }
        *(ushort4*)&nbh[n][kk][c4 * 4] = bf4(x);
    }
    __syncthreads();
    const float4* W4 = (const float4*)WT;
    const int p0 = pg * 2, p1 = pg * 2 + 1;
    float4 cacc0, cacc1;
    cacc0.x = cacc0.y = cacc0.z = cacc0.w = 0.f;
    cacc1 = cacc0;
    for (int ci = 0; ci < CH; ci += 4) {
        float4 xa = *(const float4*)&ctr[p0][ci];
        float4 xb = *(const float4*)&ctr[p1][ci];
        #pragma unroll
        for (int u = 0; u < 4; ++u) {
            float4 w = W4[(ci + u) * 32 + cog];
            float fa = ((const float*)&xa)[u];
            float fb = ((const float*)&xb)[u];
            FMA4(cacc0, w, fa); FMA4(cacc1, w, fb);
        }
    }
    float4 t00 = cacc0, t01 = cacc0, t02 = cacc0;
    float4 t10 = cacc1, t11 = cacc1, t12 = cacc1;
    for (int dk = 0; dk < 3; ++dk) {
        const float4* Wd = W4 + (size_t)(1 + dk) * (CH * 32);
        const unsigned short* a00 = &nbh[p0][0 * 3 + dk][0];
        const unsigned short* a01 = &nbh[p0][1 * 3 + dk][0];
        const unsigned short* a02 = &nbh[p0][2 * 3 + dk][0];
        const unsigned short* a10 = &nbh[p1][0 * 3 + dk][0];
        const unsigned short* a11 = &nbh[p1][1 * 3 + dk][0];
        const unsigned short* a12 = &nbh[p1][2 * 3 + dk][0];
        for (int ci = 0; ci < CH; ci += 4) {
            float4 x00 = bfload4(&a00[ci]);
            float4 x01 = bfload4(&a01[ci]);
            float4 x02 = bfload4(&a02[ci]);
            float4 x10 = bfload4(&a10[ci]);
            float4 x11 = bfload4(&a11[ci]);
            float4 x12 = bfload4(&a12[ci]);
            #pragma unroll
            for (int u = 0; u < 4; ++u) {
                float4 w = Wd[(ci + u) * 32 + cog];
                FMA4(t00, w, ((const float*)&x00)[u]);
                FMA4(t01, w, ((const float*)&x01)[u]);
                FMA4(t02, w, ((const float*)&x02)[u]);
                FMA4(t10, w, ((const float*)&x10)[u]);
                FMA4(t11, w, ((const float*)&x11)[u]);
                FMA4(t12, w, ((const float*)&x12)[u]);
            }
        }
    }
    {
        size_t base0 = ((size_t)(b * NP + n0 + p0) * 3) * CH + cog * 4;
        *(float4*)&YA[base0 + 0 * CH] = t00;
        *(float4*)&YA[base0 + 1 * CH] = t01;
        *(float4*)&YA[base0 + 2 * CH] = t02;
        size_t base1 = ((size_t)(b * NP + n0 + p1) * 3) * CH + cog * 4;
        *(float4*)&YA[base1 + 0 * CH] = t10;
        *(float4*)&YA[base1 + 1 * CH] = t11;
        *(float4*)&YA[base1 + 2 * CH] = t12;
    }
    float s4[4], q4[4];
    s4[0] = t00.x + t01.x + t02.x + t10.x + t11.x + t12.x;
    s4[1] = t00.y + t01.y + t02.y + t10.y + t11.y + t12.y;
    s4[2] = t00.z + t01.z + t02.z + t10.z + t11.z + t12.z;
    s4[3] = t00.w + t01.w + t02.w + t10.w + t11.w + t12.w;
    q4[0] = t00.x*t00.x + t01.x*t01.x + t02.x*t02.x + t10.x*t10.x + t11.x*t11.x + t12.x*t12.x;
    q4[1] = t00.y*t00.y + t01.y*t01.y + t02.y*t02.y + t10.y*t10.y + t11.y*t11.y + t12.y*t12.y;
    q4[2] = t00.z*t00.z + t01.z*t01.z + t02.z*t02.z + t10.z*t10.z + t11.z*t11.z + t12.z*t12.z;
    q4[3] = t00.w*t00.w + t01.w*t01.w + t02.w*t02.w + t10.w*t10.w + t11.w*t11.w + t12.w*t12.w;
    __syncthreads();
    float* red = (float*)&nbh[0][0][0];
    #pragma unroll
    for (int j = 0; j < 4; ++j) {
        red[((pg * 32 + cog) * 4 + j) * 2 + 0] = s4[j];
        red[((pg * 32 + cog) * 4 + j) * 2 + 1] = q4[j];
    }
    __syncthreads();
    if (threadIdx.x < CH) {
        int c = threadIdx.x;
        float ss = 0.f, qq = 0.f;
        #pragma unroll
        for (int g = 0; g < 8; ++g) {
            ss += red[((g * 32 + (c >> 2)) * 4 + (c & 3)) * 2 + 0];
            qq += red[((g * 32 + (c >> 2)) * 4 + (c & 3)) * 2 + 1];
        }
        PART[((size_t)(b * (NP / CA_PTS) + chunk) * 256 + c) * 2 + 0] = ss;
        PART[((size_t)(b * (NP / CA_PTS) + chunk) * 256 + c) * 2 + 1] = qq;
    }
}

// ---------------- angle convA (nch = 128, unchanged) ----------------
__global__ void angA_kernel(const float* __restrict__ COSA, const float* __restrict__ WT,
                            float* __restrict__ YA, float* __restrict__ PART) {
    __shared__ float ca[32][10];
    int b = blockIdx.x / (NP / 32);
    int chunk = blockIdx.x % (NP / 32);
    int n0 = chunk * 32;
    int co = threadIdx.x;
    for (int v = threadIdx.x; v < 320; v += 128) {
        int nn = v / 10, kk = v % 10;
        ca[nn][kk] = COSA[(b * NP + n0 + nn) * KNB + kk];
    }
    float w0 = WT[co], w1 = WT[CH + co], w2 = WT[2 * CH + co];
    __syncthreads();
    float sum = 0.f, sq = 0.f;
    for (int nn = 0; nn < 32; nn++) {
        #pragma unroll
        for (int t = 0; t < 3; t++) {
            float v = w0 * ca[nn][3 * t] + w1 * ca[nn][3 * t + 1] + w2 * ca[nn][3 * t + 2];
            YA[((b * NP + n0 + nn) * 3 + t) * CH + co] = v;
            sum += v; sq += v * v;
        }
    }
    PART[((b * (NP / 32) + chunk) * 256 + co) * 2 + 0] = sum;
    PART[((b * (NP / 32) + chunk) * 256 + co) * 2 + 1] = sq;
}

// ---------------- shared GEMM core: 16 pts/block, 4 co/thread ----------------
template <int CIN, int NCOG>
__device__ __forceinline__ void gemm_16pt(const float* lds, const float* __restrict__ WT,
                                          int cog, int pg, float4 acc[4]) {
    const float4* W4 = (const float4*)WT;
    const float* xb = lds + pg * 4 * CIN;
    for (int ci = 0; ci < CIN; ci += 4) {
        float4 x0 = *(const float4*)&xb[0 * CIN + ci];
        float4 x1 = *(const float4*)&xb[1 * CIN + ci];
        float4 x2 = *(const float4*)&xb[2 * CIN + ci];
        float4 x3 = *(const float4*)&xb[3 * CIN + ci];
        #pragma unroll
        for (int u = 0; u < 4; ++u) {
            float4 w = W4[(ci + u) * NCOG + cog];
            float f0 = ((const float*)&x0)[u];
            float f1 = ((const float*)&x1)[u];
            float f2 = ((const float*)&x2)[u];
            float f3 = ((const float*)&x3)[u];
            FMA4(acc[0], w, f0); FMA4(acc[1], w, f1);
            FMA4(acc[2], w, f2); FMA4(acc[3], w, f3);
        }
    }
}

template <int NCOG>
__device__ __forceinline__ void reduce_stats(const float* s4, const float* q4,
                                             float* red, float* __restrict__ PART,
                                             int b, int chunk, int nchunks,
                                             int pg, int cog) {
    constexpr int COUT = NCOG * 4;
    __syncthreads();
    #pragma unroll
    for (int j = 0; j < 4; ++j) {
        red[((pg * NCOG + cog) * 4 + j) * 2 + 0] = s4[j];
        red[((pg * NCOG + cog) * 4 + j) * 2 + 1] = q4[j];
    }
    __syncthreads();
    int c = threadIdx.x;
    if (c < COUT) {
        float ss = 0.f, qq = 0.f;
        #pragma unroll
        for (int g = 0; g < 4; ++g) {
            ss += red[((g * NCOG + (c >> 2)) * 4 + (c & 3)) * 2 + 0];
            qq += red[((g * NCOG + (c >> 2)) * 4 + (c & 3)) * 2 + 1];
        }
        PART[((size_t)(b * nchunks + chunk) * 256 + c) * 2 + 0] = ss;
        PART[((size_t)(b * nchunks + chunk) * 256 + c) * 2 + 1] = qq;
    }
}

// out + per-channel partial-stat accumulation for the 16-pt kernels
template <int NCOG>
__device__ __forceinline__ void out16(const float4 acc[4], float* __restrict__ OUT,
                                      int b, int n0, int pg, int cog,
                                      float s4[4], float q4[4]) {
    constexpr int COUT = NCOG * 4;
    #pragma unroll
    for (int p = 0; p < 4; ++p) {
        *(float4*)&OUT[(size_t)(b * NP + n0 + pg * 4 + p) * COUT + cog * 4] = acc[p];
        s4[0] += acc[p].x; s4[1] += acc[p].y; s4[2] += acc[p].z; s4[3] += acc[p].w;
        q4[0] += acc[p].x * acc[p].x; q4[1] += acc[p].y * acc[p].y;
        q4[2] += acc[p].z * acc[p].z; q4[3] += acc[p].w * acc[p].w;
    }
}

// ---------------- per-pixel GEMM: fused input norm+act, optional output stats ----------------
template <int CIN, int NCOG>
__global__ void pixel_gemm_t(const float* __restrict__ IN_, const float* __restrict__ WT,
                             float* __restrict__ OUT, const float* __restrict__ STATS,
                             int slot, int act, float* __restrict__ PART) {
    constexpr int COUT = NCOG * 4;
    constexpr int BD = 4 * NCOG;
    __shared__ __align__(16) float ldsin[16 * CIN];
    int b = blockIdx.x / (NP / 16);
    int chunk = blockIdx.x % (NP / 16);
    int n0 = chunk * 16;
    int cog = threadIdx.x & (NCOG - 1);
    int pg = threadIdx.x / NCOG;
    constexpr int nv4 = 16 * CIN / 4;
    if (slot >= 0) {
        int cbase = (4 * threadIdx.x) & 127;     // channel set is constant per thread
        const float* st = &STATS[((slot * BN + b) * 256 + cbase) * 2];
        float m0 = st[0], r0 = st[1], m1 = st[2], r1 = st[3];
        float m2 = st[4], r2 = st[5], m3 = st[6], r3 = st[7];
        for (int v4 = threadIdx.x; v4 < nv4; v4 += BD) {
            float4 x = *(const float4*)&IN_[(size_t)(b * NP + n0) * CIN + 4 * v4];
            float v0 = (x.x - m0) * r0, v1 = (x.y - m1) * r1;
            float v2 = (x.z - m2) * r2, v3 = (x.w - m3) * r3;
            if (act) {
                x.x = (v0 >= 0.f) ? v0 : 0.2f * v0;
                x.y = (v1 >= 0.f) ? v1 : 0.2f * v1;
                x.z = (v2 >= 0.f) ? v2 : 0.2f * v2;
                x.w = (v3 >= 0.f) ? v3 : 0.2f * v3;
            } else {
                x.x = fmaxf(v0, 0.f); x.y = fmaxf(v1, 0.f);
                x.z = fmaxf(v2, 0.f); x.w = fmaxf(v3, 0.f);
            }
            *(float4*)&ldsin[4 * v4] = x;
        }
    } else {
        for (int v4 = threadIdx.x; v4 < nv4; v4 += BD)
            *(float4*)&ldsin[4 * v4] =
                *(const float4*)&IN_[(size_t)(b * NP + n0) * CIN + 4 * v4];
    }
    __syncthreads();
    float4 acc[4];
    #pragma unroll
    for (int p = 0; p < 4; ++p) acc[p].x = acc[p].y = acc[p].z = acc[p].w = 0.f;
    gemm_16pt<CIN, NCOG>(ldsin, WT, cog, pg, acc);
    float s4[4] = {0,0,0,0}, q4[4] = {0,0,0,0};
    out16<NCOG>(acc, OUT, b, n0, pg, cog, s4, q4);
    if (PART)
        reduce_stats<NCOG>(s4, q4, ldsin, PART, b, chunk, NP / 16, pg, cog);
}

// ---------------- stats finalize (unchanged) ----------------
__global__ void stats_final(const float* __restrict__ PART, float* __restrict__ STATS,
                            int S, int Cc, int slot, int nch) {
    __shared__ float ssum[256], ssq[256];
    int bc = blockIdx.x;
    int b = bc / Cc, c = bc % Cc;
    float sum = 0.f, sq = 0.f;
    for (int ch = threadIdx.x; ch < nch; ch += 256) {
        sum += PART[((b * nch + ch) * 256 + c) * 2 + 0];
        sq  += PART[((b * nch + ch) * 256 + c) * 2 + 1];
    }
    ssum[threadIdx.x] = sum; ssq[threadIdx.x] = sq;
    __syncthreads();
    for (int s = 128; s > 0; s >>= 1) {
        if (threadIdx.x < s) {
            ssum[threadIdx.x] += ssum[threadIdx.x + s];
            ssq[threadIdx.x]  += ssq[threadIdx.x + s];
        }
        __syncthreads();
    }
    if (threadIdx.x == 0) {
        float mean = ssum[0] / (float)S;
        float var = fmaxf(ssq[0] / (float)S - mean * mean, 0.f);
        STATS[((slot * BN + b) * 256 + c) * 2 + 0] = mean;
        STATS[((slot * BN + b) * 256 + c) * 2 + 1] = rsqrtf(var + EPSI);
    }
}

// ---------------- fused U-GEMM + gather + max + stats (nch = 256) ----------------
// slot >= 0: apply leaky-norm to staged X rows
template <int NCOG>
__global__ void gathermax_t(const float* __restrict__ X, const float* __restrict__ Wu,
                            const float* __restrict__ V, const int* __restrict__ IDX,
                            float* __restrict__ M, float* __restrict__ PART,
                            const float* __restrict__ STATS, int slot) {
    constexpr int COUT = NCOG * 4;
    __shared__ __align__(16) float rows[GM_PTS * CH];
    int b = blockIdx.x / (NP / GM_PTS);
    int chunk = blockIdx.x % (NP / GM_PTS);
    int n0 = chunk * GM_PTS;
    int cog = threadIdx.x & (NCOG - 1);
    int pg = threadIdx.x / NCOG;
    if (slot >= 0) {
        int c0 = (4 * threadIdx.x) & 127;     // fixed channel set per thread
        const float* st = &STATS[((slot * BN + b) * 256 + c0) * 2];
        float m0 = st[0], r0 = st[1], m1 = st[2], r1 = st[3];
        float m2 = st[4], r2 = st[5], m3 = st[6], r3 = st[7];
        for (int v4 = threadIdx.x; v4 < GM_PTS * CH / 4; v4 += COUT) {
            float4 x = *(const float4*)&X[(size_t)(b * NP + n0) * CH + v4 * 4];
            float v0 = (x.x - m0) * r0, v1 = (x.y - m1) * r1;
            float v2 = (x.z - m2) * r2, v3 = (x.w - m3) * r3;
            x.x = (v0 >= 0.f) ? v0 : 0.2f * v0;
            x.y = (v1 >= 0.f) ? v1 : 0.2f * v1;
            x.z = (v2 >= 0.f) ? v2 : 0.2f * v2;
            x.w = (v3 >= 0.f) ? v3 : 0.2f * v3;
            *(float4*)&rows[v4 * 4] = x;
        }
    } else {
        for (int v4 = threadIdx.x; v4 < GM_PTS * CH / 4; v4 += COUT)
            *(float4*)&rows[v4 * 4] = *(const float4*)&X[(size_t)(b * NP + n0) * CH + v4 * 4];
    }
    __syncthreads();
    float4 acc[4];
    #pragma unroll
    for (int p = 0; p < 4; ++p) acc[p].x = acc[p].y = acc[p].z = acc[p].w = 0.f;
    gemm_16pt<CH, NCOG>(rows, Wu, cog, pg, acc);
    float s4[4] = {0,0,0,0}, q4[4] = {0,0,0,0};
    #pragma unroll
    for (int p = 0; p < 4; ++p) {
        int nn = n0 + pg * 4 + p;
        float4 u = acc[p];
        float4 best; best.x = best.y = best.z = best.w = -3.4e38f;
        for (int k = 0; k < KNB; ++k) {
            int j = clampj(IDX[(b * NP + nn) * KNB + k]);
            float4 vv = *(const float4*)&V[(size_t)(b * NP + j) * COUT + cog * 4];
            vv.x += u.x; vv.y += u.y; vv.z += u.z; vv.w += u.w;
            s4[0] += vv.x; s4[1] += vv.y; s4[2] += vv.z; s4[3] += vv.w;
            q4[0] += vv.x * vv.x; q4[1] += vv.y * vv.y;
            q4[2] += vv.z * vv.z; q4[3] += vv.w * vv.w;
            best.x = fmaxf(best.x, vv.x); best.y = fmaxf(best.y, vv.y);
            best.z = fmaxf(best.z, vv.z); best.w = fmaxf(best.w, vv.w);
        }
        *(float4*)&M[(size_t)(b * NP + nn) * COUT + cog * 4] = best;
    }
    __syncthreads();   // rows no longer needed
    reduce_stats<NCOG>(s4, q4, rows, PART, b, chunk, NP / GM_PTS, pg, cog);
}

// ---------------- heads (fused input norms) ----------------
__global__ void head3_kernel(const float* __restrict__ F, const float* __restrict__ X1,
                             const float* __restrict__ X2, const float* __restrict__ FANG,
                             const float* __restrict__ WT, float* __restrict__ Y3,
                             float* __restrict__ PART, const float* __restrict__ STATS) {
    __shared__ __align__(16) float lds[16 * 384];
    int b = blockIdx.x / (NP / 16);
    int chunk = blockIdx.x % (NP / 16);
    int n0 = chunk * 16;
    int cog = threadIdx.x & 31;
    int pg = threadIdx.x >> 5;
    const float* S1 = &STATS[((size_t)(1 * BN + b) * 256) * 2];
    const float* S5 = &STATS[((size_t)(5 * BN + b) * 256) * 2];
    const float* S3 = &STATS[((size_t)(3 * BN + b) * 256) * 2];
    for (int v4 = threadIdx.x; v4 < 16 * 96; v4 += 128) {
        int nn = v4 / 96, q4 = v4 % 96;
        int part = q4 >> 5, c4 = q4 & 31;
        size_t base = (size_t)(b * NP + n0 + nn) * CH + c4 * 4;
        float4 val;
        if (part == 0) val = *(const float4*)&F[base];
        else {
            const float* src = (part == 1) ? X1 : X2;
            const float* SX = (part == 1) ? S1 : S5;
            float4 xx = *(const float4*)&src[base];
            float4 aa = *(const float4*)&FANG[base];
            float4 sx0 = *(const float4*)&SX[c4 * 8];
            float4 sx1 = *(const float4*)&SX[c4 * 8 + 4];
            float4 sa0 = *(const float4*)&S3[c4 * 8];
            float4 sa1 = *(const float4*)&S3[c4 * 8 + 4];
            val.x = fmaxf((xx.x - sx0.x) * sx0.y, 0.f) + fmaxf((aa.x - sa0.x) * sa0.y, 0.f);
            val.y = fmaxf((xx.y - sx0.z) * sx0.w, 0.f) + fmaxf((aa.y - sa0.z) * sa0.w, 0.f);
            val.z = fmaxf((xx.z - sx1.x) * sx1.y, 0.f) + fmaxf((aa.z - sa1.x) * sa1.y, 0.f);
            val.w = fmaxf((xx.w - sx1.z) * sx1.w, 0.f) + fmaxf((aa.w - sa1.z) * sa1.w, 0.f);
        }
        *(float4*)&lds[v4 * 4] = val;
    }
    __syncthreads();
    float4 acc[4];
    #pragma unroll
    for (int p = 0; p < 4; ++p) acc[p].x = acc[p].y = acc[p].z = acc[p].w = 0.f;
    gemm_16pt<384, 32>(lds, WT, cog, pg, acc);
    float s4[4] = {0,0,0,0}, q4[4] = {0,0,0,0};
    out16<32>(acc, Y3, b, n0, pg, cog, s4, q4);
    reduce_stats<32>(s4, q4, lds, PART, b, chunk, NP / 16, pg, cog);
}

__global__ void head3o_kernel(const float* __restrict__ F, const float* __restrict__ X1O,
                              const float* __restrict__ X2O, const float* __restrict__ WT,
                              float* __restrict__ Y3O, float* __restrict__ PART,
                              const float* __restrict__ STATS) {
    __shared__ __align__(16) float lds[16 * 512];
    int b = blockIdx.x / (NP / 16);
    int chunk = blockIdx.x % (NP / 16);
    int n0 = chunk * 16;
    int cog = threadIdx.x & 31;
    int pg = threadIdx.x >> 5;
    const float* S6 = &STATS[((size_t)(6 * BN + b) * 256) * 2];
    const float* S7 = &STATS[((size_t)(7 * BN + b) * 256) * 2];
    for (int v4 = threadIdx.x; v4 < 16 * 128; v4 += 128) {
        int nn = v4 >> 7, q4 = v4 & 127;
        float4 val;
        if (q4 < 32) {
            val = *(const float4*)&F[(size_t)(b * NP + n0 + nn) * CH + q4 * 4];
        } else if (q4 < 64) {
            int c4 = q4 - 32;
            float4 x = *(const float4*)&X1O[(size_t)(b * NP + n0 + nn) * CH + c4 * 4];
            float4 s0 = *(const float4*)&S6[c4 * 8];
            float4 s1 = *(const float4*)&S6[c4 * 8 + 4];
            float v0 = (x.x - s0.x) * s0.y, v1 = (x.y - s0.z) * s0.w;
            float v2 = (x.z - s1.x) * s1.y, v3 = (x.w - s1.z) * s1.w;
            val.x = (v0 >= 0.f) ? v0 : 0.2f * v0;
            val.y = (v1 >= 0.f) ? v1 : 0.2f * v1;
            val.z = (v2 >= 0.f) ? v2 : 0.2f * v2;
            val.w = (v3 >= 0.f) ? v3 : 0.2f * v3;
        } else {
            int c4 = q4 - 64;   // channels 0..255
            float4 x = *(const float4*)&X2O[(size_t)(b * NP + n0 + nn) * 256 + c4 * 4];
            float4 s0 = *(const float4*)&S7[c4 * 8];
            float4 s1 = *(const float4*)&S7[c4 * 8 + 4];
            float v0 = (x.x - s0.x) * s0.y, v1 = (x.y - s0.z) * s0.w;
            float v2 = (x.z - s1.x) * s1.y, v3 = (x.w - s1.z) * s1.w;
            val.x = (v0 >= 0.f) ? v0 : 0.2f * v0;
            val.y = (v1 >= 0.f) ? v1 : 0.2f * v1;
            val.z = (v2 >= 0.f) ? v2 : 0.2f * v2;
            val.w = (v3 >= 0.f) ? v3 : 0.2f * v3;
        }
        *(float4*)&lds[v4 * 4] = val;
    }
    __syncthreads();
    float4 acc[4];
    #pragma unroll
    for (int p = 0; p < 4; ++p) acc[p].x = acc[p].y = acc[p].z = acc[p].w = 0.f;
    gemm_16pt<512, 32>(lds, WT, cog, pg, acc);
    float s4[4] = {0,0,0,0}, q4[4] = {0,0,0,0};
    out16<32>(acc, Y3O, b, n0, pg, cog, s4, q4);
    reduce_stats<32>(s4, q4, lds, PART, b, chunk, NP / 16, pg, cog);
}

// ---------------- final ----------------
__global__ void final_kernel(const float* __restrict__ Y3, const float* __restrict__ Y3O,
                             const float* __restrict__ STATS, float* __restrict__ out) {
    __shared__ float T[64][129];
    int b = blockIdx.x / (NP / 64);
    int n0 = (blockIdx.x % (NP / 64)) * 64;
    int co = threadIdx.x;
    float m3 = STATS[((8 * BN + b) * 256 + co) * 2 + 0];
    float r3 = STATS[((8 * BN + b) * 256 + co) * 2 + 1];
    float m3o = STATS[((9 * BN + b) * 256 + co) * 2 + 0];
    float r3o = STATS[((9 * BN + b) * 256 + co) * 2 + 1];
    for (int j = 0; j < 64; j++) {
        size_t idx = (size_t)(b * NP + n0 + j) * CH + co;
        float v3 = (Y3[idx] - m3) * r3;
        v3 = (v3 >= 0.f) ? v3 : 0.2f * v3;
        float v3o = (Y3O[idx] - m3o) * r3o;
        v3o = (v3o >= 0.f) ? v3o : 0.2f * v3o;
        T[j][co] = v3 + v3o;
    }
    __syncthreads();
    for (int rr = 0; rr < 64; rr++) {
        int r = rr * 2 + (threadIdx.x >> 6);
        int j = threadIdx.x & 63;
        out[(size_t)(b * CH + r) * NP + n0 + j] = T[j][r];
    }
}

// ---------------- launch ----------------
extern "C" void kernel_launch(void* const* d_in, const int* in_sizes, int n_in,
                              void* d_out, int out_size, void* d_ws, size_t ws_size,
                              hipStream_t stream) {
    const float* coords   = (const float*)d_in[0];
    const float* features = (const float*)d_in[1];
    const float* W1   = (const float*)d_in[2];
    const float* W2   = (const float*)d_in[3];
    const float* W3   = (const float*)d_in[4];
    const float* W3o  = (const float*)d_in[5];
    const float* a1wA = (const float*)d_in[6];
    const float* a1wB = (const float*)d_in[8];
    const float* a2wA = (const float*)d_in[10];
    const float* a2wB = (const float*)d_in[12];
    const float* angwA = (const float*)d_in[14];
    const float* angwB = (const float*)d_in[16];
    float* out = (float*)d_out;
    float* ws = (float*)d_ws;
    (void)ws_size; (void)in_sizes; (void)n_in; (void)out_size;

    size_t off = 0;
    float* WA1T  = ws + off; off += 4 * CH * CH;
    float* WA2T  = ws + off; off += 4 * CH * CH;
    float* WB1T  = ws + off; off += 3 * CH * CH;
    float* WB2T  = ws + off; off += 3 * CH * CH;
    float* WBAT  = ws + off; off += 3 * CH * CH;
    float* WANGA = ws + off; off += 512;
    float* W1U   = ws + off; off += CH * CH;
    float* W1N   = ws + off; off += CH * CH;
    float* W2U   = ws + off; off += CH * 256;
    float* W2N   = ws + off; off += CH * 256;
    float* W3T   = ws + off; off += 384 * CH;
    float* W3OT  = ws + off; off += 512 * CH;
    int*   IDX   = (int*)(ws + off); off += (size_t)BN * NP * KNB;
    float* COSA  = ws + off; off += (size_t)BN * NP * KNB;
    float* PART  = ws + off; off += (size_t)BN * 1024 * 256 * 2;
    float* STATS = ws + off; off += 10 * BN * 256 * 2;
    const size_t UNIT = (size_t)BN * NP * CH;
    float* POOL  = ws + off; off += 7 * UNIT;

    float* F    = POOL + 0 * UNIT;
    float* YA   = POOL + 1 * UNIT;  // slots 1-3
    float* X1   = POOL + 4 * UNIT;
    float* FANG = POOL + 5 * UNIT;
    float* X2   = POOL + 6 * UNIT;
    float* Y3   = POOL + 1 * UNIT;  // slot 1 (YA dead)
    float* V1   = POOL + 2 * UNIT;  // slot 2
    float* M1   = POOL + 6 * UNIT;  // slot 6 (X2 dead)  -> X1O
    float* V2   = POOL + 4 * UNIT;  // slots 4-5 (X1,FANG dead)
    float* M2   = POOL + 2 * UNIT;  // slots 2-3 (V1 dead) -> X2O
    float* Y3O  = POOL + 4 * UNIT;  // slot 4 (V2 dead)

    pack_all<<<1730, 256, 0, stream>>>(a1wA, a2wA, a1wB, a2wB, angwB, W1, W2, W3, W3o, angwA,
                                       WA1T, WA2T, WB1T, WB2T, WBAT,
                                       W1U, W1N, W2U, W2N, W3T, W3OT, WANGA);

    ftrans_kernel<<<(BN * CH * NP + 255) / 256, 256, 0, stream>>>(features, F);
    knn_kernel<<<BN * NP / 4, 256, 0, stream>>>(coords, IDX);
    cosangle_kernel<<<(BN * NP * KNB + 255) / 256, 256, 0, stream>>>(coords, IDX, COSA);

    auto sfin = [&](int S, int Cc, int slot, int nch) {
        stats_final<<<BN * Cc, 256, 0, stream>>>(PART, STATS, S, Cc, slot, nch);
    };

    // --- x1 block ---
    convA_kernel<<<BN * (NP / CA_PTS), 256, 0, stream>>>(F, IDX, WA1T, YA, PART, STATS, -1);
    sfin(3 * NP, CH, 0, NP / CA_PTS);
    pixel_gemm_t<384, 32><<<BN * (NP / 16), 128, 0, stream>>>(YA, WB1T, X1, STATS, 0, 0, PART);
    sfin(NP, CH, 1, NP / 16);

    // --- angle block ---
    angA_kernel<<<BN * (NP / 32), 128, 0, stream>>>(COSA, WANGA, YA, PART);
    sfin(3 * NP, CH, 2, NP / 32);
    pixel_gemm_t<384, 32><<<BN * (NP / 16), 128, 0, stream>>>(YA, WBAT, FANG, STATS, 2, 0, PART);
    sfin(NP, CH, 3, NP / 16);

    // --- x2 block (convA applies relu-norm slot1 to X1) ---
    convA_kernel<<<BN * (NP / CA_PTS), 256, 0, stream>>>(X1, IDX, WA2T, YA, PART, STATS, 1);
    sfin(3 * NP, CH, 4, NP / CA_PTS);
    pixel_gemm_t<384, 32><<<BN * (NP / 16), 128, 0, stream>>>(YA, WB2T, X2, STATS, 4, 0, PART);
    sfin(NP, CH, 5, NP / 16);

    // --- head3 (fuses relu-norm of X1/X2/FANG, slots 1/5/3) ---
    head3_kernel<<<BN * (NP / 16), 128, 0, stream>>>(F, X1, X2, FANG, W3T, Y3, PART, STATS);
    sfin(NP, CH, 8, NP / 16);

    // --- x1o path ---
    pixel_gemm_t<128, 32><<<BN * (NP / 16), 128, 0, stream>>>(F, W1N, V1, STATS, -1, 0, nullptr);
    gathermax_t<32><<<BN * (NP / GM_PTS), 128, 0, stream>>>(F, W1U, V1, IDX, M1, PART, STATS, -1);
    sfin(NP * KNB, CH, 6, NP / GM_PTS);

    // --- x2o path (consumers apply leaky-norm slot6 to M1) ---
    pixel_gemm_t<128, 64><<<BN * (NP / 16), 256, 0, stream>>>(M1, W2N, V2, STATS, 6, 1, nullptr);
    gathermax_t<64><<<BN * (NP / GM_PTS), 256, 0, stream>>>(M1, W2U, V2, IDX, M2, PART, STATS, 6);
    sfin(NP * KNB, 256, 7, NP / GM_PTS);

    // --- head3o (fuses leaky-norm of M1/M2, slots 6/7) + final ---
    head3o_kernel<<<BN * (NP / 16), 128, 0, stream>>>(F, M1, M2, W3OT, Y3O, PART, STATS);
    sfin(NP, CH, 9, NP / 16);
    final_kernel<<<BN * (NP / 64), 128, 0, stream>>>(Y3, Y3O, STATS, out);
}